// Round 2
// baseline (172.412 us; speedup 1.0000x reference)
//
#include <hip/hip_runtime.h>

// BloomStageLoss: label-smoothed CE + transition penalty, scalar mean.
// B = 4194304 rows x C=5 fp32 logits + int32 targets -> 1 float.
// ~117 MB read => ~19 us HBM floor at 6.3 TB/s.
//
// R1 theory: R0 kernel was latency/atomic-bound (61.6 us even L3-resident).
// Fix: coalesced tile loads + LDS transpose (stride-5 float4 = odd stride in
// quad-banks => minimum conflicts), 1024 blocks, per-block partial array +
// last-block-done final reduce (kills 16k same-address double atomics and the
// separate finalize kernel node).

constexpr int C = 5;
constexpr int BLOCK = 256;
constexpr int ROWS_PER_TILE = 4 * BLOCK;              // 1024 rows / tile
constexpr int F4_PER_TILE = ROWS_PER_TILE * C / 4;    // 1280 float4 = 20 KB
constexpr int NBLOCKS = 1024;

__device__ __forceinline__ float trans_w(int d) {
    d = d < 0 ? -d : d;
    return (d == 0) ? 0.0f : (d == 1) ? 0.5f : (d == 2) ? 1.0f : 2.0f;
}

__device__ __forceinline__ float row_loss(float a0, float a1, float a2,
                                          float a3, float a4, int t) {
    float m = fmaxf(fmaxf(fmaxf(a0, a1), fmaxf(a2, a3)), a4);
    float e0 = __expf(a0 - m);
    float e1 = __expf(a1 - m);
    float e2 = __expf(a2 - m);
    float e3 = __expf(a3 - m);
    float e4 = __expf(a4 - m);
    float s  = e0 + e1 + e2 + e3 + e4;
    float ls = __logf(s);
    float inv = 1.0f / s;

    float lp0 = a0 - m - ls;
    float lp1 = a1 - m - ls;
    float lp2 = a2 - m - ls;
    float lp3 = a3 - m - ls;
    float lp4 = a4 - m - ls;
    float sumlp = lp0 + lp1 + lp2 + lp3 + lp4;
    float lpt = (t == 0) ? lp0 : (t == 1) ? lp1 : (t == 2) ? lp2
              : (t == 3) ? lp3 : lp4;

    float pen = e0 * trans_w(t)     + e1 * trans_w(t - 1) + e2 * trans_w(t - 2)
              + e3 * trans_w(t - 3) + e4 * trans_w(t - 4);
    pen *= inv;

    // smoothing 0.1: w_target = 0.9, w_other = 0.025 => 0.875*lpt + 0.025*sumlp
    return -(0.875f * lpt + 0.025f * sumlp) + 0.1f * pen;
}

__global__ __launch_bounds__(BLOCK) void bloom_fused(
        const float* __restrict__ x, const int* __restrict__ tgt,
        double* __restrict__ partial, unsigned int* __restrict__ counter,
        float* __restrict__ out, int nTiles, int B) {
    __shared__ float4 tile4[F4_PER_TILE];   // 20 KB
    __shared__ double wsum[4];
    __shared__ double dsum[4];
    __shared__ bool isLast;

    const int tid = threadIdx.x;
    const float4* __restrict__ x4 = (const float4*)x;
    const int4* __restrict__ tgt4 = (const int4*)tgt;

    float local = 0.0f;

    for (int tile = blockIdx.x; tile < nTiles; tile += gridDim.x) {
        const long base4 = (long)tile * F4_PER_TILE;
        // perfectly coalesced: lane-contiguous dwordx4
        float4 v0 = x4[base4 + 0 * BLOCK + tid];
        float4 v1 = x4[base4 + 1 * BLOCK + tid];
        float4 v2 = x4[base4 + 2 * BLOCK + tid];
        float4 v3 = x4[base4 + 3 * BLOCK + tid];
        float4 v4 = x4[base4 + 4 * BLOCK + tid];
        int4 t4 = tgt4[(long)tile * BLOCK + tid];

        tile4[0 * BLOCK + tid] = v0;
        tile4[1 * BLOCK + tid] = v1;
        tile4[2 * BLOCK + tid] = v2;
        tile4[3 * BLOCK + tid] = v3;
        tile4[4 * BLOCK + tid] = v4;
        __syncthreads();

        // thread's 4 rows = 20 contiguous floats = 5 float4 (stride-5: odd in
        // quad-bank units => minimum LDS conflicts)
        float4 r0 = tile4[tid * 5 + 0];
        float4 r1 = tile4[tid * 5 + 1];
        float4 r2 = tile4[tid * 5 + 2];
        float4 r3 = tile4[tid * 5 + 3];
        float4 r4 = tile4[tid * 5 + 4];

        local += row_loss(r0.x, r0.y, r0.z, r0.w, r1.x, t4.x);
        local += row_loss(r1.y, r1.z, r1.w, r2.x, r2.y, t4.y);
        local += row_loss(r2.z, r2.w, r3.x, r3.y, r3.z, t4.z);
        local += row_loss(r3.w, r4.x, r4.y, r4.z, r4.w, t4.w);
        __syncthreads();
    }

    // tail rows (if B % 1024 != 0) -> last block, thread-per-row
    if (blockIdx.x == gridDim.x - 1) {
        for (int r = nTiles * ROWS_PER_TILE + tid; r < B; r += BLOCK) {
            local += row_loss(x[(long)r * C + 0], x[(long)r * C + 1],
                              x[(long)r * C + 2], x[(long)r * C + 3],
                              x[(long)r * C + 4], tgt[r]);
        }
    }

    // block reduction (float within wave, double across waves)
    #pragma unroll
    for (int off = 32; off > 0; off >>= 1)
        local += __shfl_down(local, off, 64);
    const int lane = tid & 63;
    const int wid = tid >> 6;
    if (lane == 0) wsum[wid] = (double)local;
    __syncthreads();

    if (tid == 0) {
        double bs = wsum[0] + wsum[1] + wsum[2] + wsum[3];
        // device-scope atomic store => coherent across XCDs, no contention
        atomicExch((unsigned long long*)&partial[blockIdx.x],
                   (unsigned long long)__double_as_longlong(bs));
        __threadfence();
        unsigned prev = atomicAdd(counter, 1u);
        isLast = (prev == (unsigned)(gridDim.x - 1));
    }
    __syncthreads();

    if (isLast) {   // block-uniform
        double s = 0.0;
        for (int i = tid; i < (int)gridDim.x; i += BLOCK) {
            unsigned long long bits =
                atomicAdd((unsigned long long*)&partial[i], 0ull); // atomic read
            s += __longlong_as_double((long long)bits);
        }
        #pragma unroll
        for (int off = 32; off > 0; off >>= 1)
            s += __shfl_down(s, off, 64);
        if (lane == 0) dsum[wid] = s;
        __syncthreads();
        if (tid == 0)
            out[0] = (float)((dsum[0] + dsum[1] + dsum[2] + dsum[3]) / (double)B);
    }
}

extern "C" void kernel_launch(void* const* d_in, const int* in_sizes, int n_in,
                              void* d_out, int out_size, void* d_ws, size_t ws_size,
                              hipStream_t stream) {
    const float* x = (const float*)d_in[0];
    const int* tgt = (const int*)d_in[1];
    float* out = (float*)d_out;

    int B = in_sizes[1];
    int nTiles = B / ROWS_PER_TILE;
    int blocks = NBLOCKS;
    if (nTiles < blocks) blocks = (nTiles > 0) ? nTiles : 1;

    double* partial = (double*)d_ws;
    unsigned int* counter = (unsigned int*)((char*)d_ws + blocks * sizeof(double));

    // only the counter needs zeroing (partials are pure writes)
    hipMemsetAsync(counter, 0, sizeof(unsigned int), stream);

    bloom_fused<<<blocks, BLOCK, 0, stream>>>(x, tgt, partial, counter, out,
                                              nTiles, B);
}